// Round 1
// baseline (549.806 us; speedup 1.0000x reference)
//
#include <hip/hip_runtime.h>
#include <cstdint>
#include <cstddef>

// ---------------------------------------------------------------------------
// RelativeTransformerEncoderLayer on MI355X (gfx950)
// T=2048 B=2 D=1024 NH=8 DH=64 DFF=4096
// Pipeline: cvt weights->bf16 | dual LN | QKV GEMM x2 | rk GEMM x2 |
//   qkv_post (bias+scale+head layout) | v transpose | rk reverse |
//   flash attention w/ rel-shift band GEMM (fwd+bwd fused via grid.z) |
//   wo GEMM (+bo +x -> h) | LN3 | FFN1 (relu) | FFN2 (+b2 +h -> out)
// ---------------------------------------------------------------------------

typedef unsigned short ushort_t;
typedef __bf16 bf16x8 __attribute__((ext_vector_type(8)));
typedef float f32x4 __attribute__((ext_vector_type(4)));
typedef unsigned short us8 __attribute__((ext_vector_type(8)));
typedef unsigned short us4 __attribute__((ext_vector_type(4)));

#define DEV static __device__ __forceinline__

DEV ushort_t f2bf(float x) {
  union { float f; unsigned u; } v; v.f = x;
  unsigned r = (v.u + 0x7FFFu + ((v.u >> 16) & 1u)) >> 16;
  return (ushort_t)r;
}
DEV float bf2f(ushort_t h) {
  union { unsigned u; float f; } v; v.u = ((unsigned)h) << 16;
  return v.f;
}
DEV f32x4 mfma16(bf16x8 a, bf16x8 b, f32x4 c) {
  return __builtin_amdgcn_mfma_f32_16x16x32_bf16(a, b, c, 0, 0, 0);
}

// ---------------- workspace layout (bytes, all 1MB-aligned) ----------------
constexpr size_t O_QKV_F  = 0;                    // 1536x1024 bf16 = 3MB
constexpr size_t O_QKV_B  = 3145728;
constexpr size_t O_RNET_F = 6291456;              // 512x1024 bf16 = 1MB
constexpr size_t O_RNET_B = 7340032;
constexpr size_t O_WO     = 8388608;              // 1024x1024 bf16 = 2MB
constexpr size_t O_W1     = 10485760;             // 4096x1024 bf16 = 8MB
constexpr size_t O_W2     = 18874368;             // 1024x4096 bf16 = 8MB
constexpr size_t O_RKREV_F= 27262976;             // [8][2048][64] bf16 = 2MB
constexpr size_t O_RKREV_B= 29360128;
constexpr size_t O_QAC_F  = 31457280;             // [16][2048][64] bf16 = 4MB each
constexpr size_t O_QBD_F  = 35651584;
constexpr size_t O_KK_F   = 39845888;
constexpr size_t O_VT_F   = 44040192;             // [16][64][2048]
constexpr size_t O_QAC_B  = 48234496;
constexpr size_t O_QBD_B  = 52428800;
constexpr size_t O_KK_B   = 56623104;
constexpr size_t O_VT_B   = 60817408;
constexpr size_t O_H      = 65011712;             // 4096x1024 f32 = 16MB
constexpr size_t O_LN3    = 81788928;             // 4096x1024 bf16 = 8MB
constexpr size_t ZONE     = 90177536;             // phase-reused scratch zone
constexpr size_t O_POS    = ZONE + 0;             // 2048x1024 bf16 = 4MB   (ph1)
constexpr size_t O_LN1    = ZONE + 4194304;       // 8MB                    (ph1)
constexpr size_t O_LN2    = ZONE + 12582912;      // 8MB                    (ph1)
constexpr size_t O_HEADS_F= ZONE + 20971520;      // 4096x1536 bf16 = 12MB  (ph1)
constexpr size_t O_HEADS_B= ZONE + 33554432;      // 12MB                   (ph1)
constexpr size_t O_RKRAW_F= ZONE + 46137344;      // 2048x512 bf16 = 2MB    (ph1)
constexpr size_t O_RKRAW_B= ZONE + 48234496;      // 2MB                    (ph1)
constexpr size_t O_ACAT   = ZONE + 0;             // 4096x1024 bf16 = 8MB   (ph2, over POS+LN1.lo)
constexpr size_t O_FFNM   = ZONE + 8388608;       // 4096x4096 bf16 = 32MB  (ph3, over LN1.hi..HEADS)
// total = ZONE + 50331648 = 140,509,184 bytes (~134 MiB)

// ---------------------------- f32 -> bf16 ----------------------------------
__global__ void cvt_bf16_k(const float* __restrict__ in, ushort_t* __restrict__ out, int n4) {
  int i = blockIdx.x * 256 + threadIdx.x;
  if (i >= n4) return;
  float4 v = reinterpret_cast<const float4*>(in)[i];
  us4 o; o[0] = f2bf(v.x); o[1] = f2bf(v.y); o[2] = f2bf(v.z); o[3] = f2bf(v.w);
  reinterpret_cast<us4*>(out)[i] = o;
}

// -------------------------- LayerNorm kernels ------------------------------
// one block per row (t*2+b), 256 threads, 4 f32 per thread
__global__ __launch_bounds__(256)
void ln_dual_k(const float* __restrict__ x,
               const float* __restrict__ g1, const float* __restrict__ b1,
               const float* __restrict__ g2, const float* __restrict__ b2,
               ushort_t* __restrict__ o1, ushort_t* __restrict__ o2) {
  __shared__ float sbuf[8];
  const int row = blockIdx.x;
  const int tid = threadIdx.x;
  const float* xr = x + (size_t)row * 1024;
  float4 v = reinterpret_cast<const float4*>(xr)[tid];
  float s  = v.x + v.y + v.z + v.w;
  float s2 = v.x*v.x + v.y*v.y + v.z*v.z + v.w*v.w;
  for (int m = 32; m >= 1; m >>= 1) { s += __shfl_xor(s, m, 64); s2 += __shfl_xor(s2, m, 64); }
  int w = tid >> 6;
  if ((tid & 63) == 0) { sbuf[w] = s; sbuf[4 + w] = s2; }
  __syncthreads();
  float S  = sbuf[0] + sbuf[1] + sbuf[2] + sbuf[3];
  float S2 = sbuf[4] + sbuf[5] + sbuf[6] + sbuf[7];
  float mu  = S * (1.f / 1024.f);
  float var = S2 * (1.f / 1024.f) - mu * mu;
  float inv = rsqrtf(var + 1e-5f);
  int t = row >> 1, b = row & 1;
  size_t r2 = ((size_t)(2047 - t) * 2 + b) * 1024;
  float4 G1 = reinterpret_cast<const float4*>(g1)[tid];
  float4 B1 = reinterpret_cast<const float4*>(b1)[tid];
  float4 G2 = reinterpret_cast<const float4*>(g2)[tid];
  float4 B2 = reinterpret_cast<const float4*>(b2)[tid];
  float n0 = (v.x - mu) * inv, n1 = (v.y - mu) * inv, n2 = (v.z - mu) * inv, n3 = (v.w - mu) * inv;
  us4 a, c;
  a[0] = f2bf(n0 * G1.x + B1.x); a[1] = f2bf(n1 * G1.y + B1.y);
  a[2] = f2bf(n2 * G1.z + B1.z); a[3] = f2bf(n3 * G1.w + B1.w);
  c[0] = f2bf(n0 * G2.x + B2.x); c[1] = f2bf(n1 * G2.y + B2.y);
  c[2] = f2bf(n2 * G2.z + B2.z); c[3] = f2bf(n3 * G2.w + B2.w);
  reinterpret_cast<us4*>(o1 + (size_t)row * 1024)[tid] = a;
  reinterpret_cast<us4*>(o2 + r2)[tid] = c;
}

__global__ __launch_bounds__(256)
void ln_one_k(const float* __restrict__ x,
              const float* __restrict__ g1, const float* __restrict__ b1,
              ushort_t* __restrict__ o1) {
  __shared__ float sbuf[8];
  const int row = blockIdx.x;
  const int tid = threadIdx.x;
  const float* xr = x + (size_t)row * 1024;
  float4 v = reinterpret_cast<const float4*>(xr)[tid];
  float s  = v.x + v.y + v.z + v.w;
  float s2 = v.x*v.x + v.y*v.y + v.z*v.z + v.w*v.w;
  for (int m = 32; m >= 1; m >>= 1) { s += __shfl_xor(s, m, 64); s2 += __shfl_xor(s2, m, 64); }
  int w = tid >> 6;
  if ((tid & 63) == 0) { sbuf[w] = s; sbuf[4 + w] = s2; }
  __syncthreads();
  float S  = sbuf[0] + sbuf[1] + sbuf[2] + sbuf[3];
  float S2 = sbuf[4] + sbuf[5] + sbuf[6] + sbuf[7];
  float mu  = S * (1.f / 1024.f);
  float var = S2 * (1.f / 1024.f) - mu * mu;
  float inv = rsqrtf(var + 1e-5f);
  float4 G1 = reinterpret_cast<const float4*>(g1)[tid];
  float4 B1 = reinterpret_cast<const float4*>(b1)[tid];
  us4 a;
  a[0] = f2bf((v.x - mu) * inv * G1.x + B1.x);
  a[1] = f2bf((v.y - mu) * inv * G1.y + B1.y);
  a[2] = f2bf((v.z - mu) * inv * G1.z + B1.z);
  a[3] = f2bf((v.w - mu) * inv * G1.w + B1.w);
  reinterpret_cast<us4*>(o1 + (size_t)row * 1024)[tid] = a;
}

// ------------------------------ GEMM ---------------------------------------
// C[M,N] = A[M,K] * B[N,K]^T   (bf16 in, fp32 accum)
// EPI 0: bf16 C.  EPI 1: bf16 relu(C + bias[col]).  EPI 2: f32 C + bias[col] + resid.
// 128x128 tile, BK=64, 256 thr (2x2 waves of 64x64), XOR-swizzled LDS.
template <int EPI>
__global__ __launch_bounds__(256)
void gemm_bt(const ushort_t* __restrict__ A, const ushort_t* __restrict__ B,
             void* __restrict__ C, const float* __restrict__ bias,
             const float* __restrict__ resid, int M, int N, int K) {
  __shared__ ushort_t As[128 * 64];
  __shared__ ushort_t Bs[128 * 64];
  const int tid = threadIdx.x;
  const int lane = tid & 63;
  const int w = tid >> 6;
  const int wm = w >> 1, wn = w & 1;
  const int row0 = blockIdx.y * 128, col0 = blockIdx.x * 128;
  const int lr = lane & 15;
  const int lkb = (lane >> 4) * 8;
  const f32x4 fz = {0.f, 0.f, 0.f, 0.f};
  f32x4 acc[4][4];
#pragma unroll
  for (int i = 0; i < 4; ++i)
#pragma unroll
    for (int j = 0; j < 4; ++j) acc[i][j] = fz;

  for (int k0 = 0; k0 < K; k0 += 64) {
    __syncthreads();
#pragma unroll
    for (int it = 0; it < 4; ++it) {
      int li = it * 256 + tid;          // 0..1023
      int r = li >> 3;                  // 0..127
      int c = (li & 7) * 8;             // 0..56
      int off = (r * 128 + c * 2) ^ ((r & 7) << 4);
      us8 va = *reinterpret_cast<const us8*>(A + (size_t)(row0 + r) * K + k0 + c);
      *reinterpret_cast<us8*>((char*)As + off) = va;
      us8 vb = *reinterpret_cast<const us8*>(B + (size_t)(col0 + r) * K + k0 + c);
      *reinterpret_cast<us8*>((char*)Bs + off) = vb;
    }
    __syncthreads();
#pragma unroll
    for (int kk = 0; kk < 64; kk += 32) {
      bf16x8 af[4], bfr[4];
#pragma unroll
      for (int mi = 0; mi < 4; ++mi) {
        int r = wm * 64 + mi * 16 + lr;
        int off = (r * 128 + (kk + lkb) * 2) ^ ((r & 7) << 4);
        af[mi] = *reinterpret_cast<const bf16x8*>((char*)As + off);
      }
#pragma unroll
      for (int ni = 0; ni < 4; ++ni) {
        int r = wn * 64 + ni * 16 + lr;
        int off = (r * 128 + (kk + lkb) * 2) ^ ((r & 7) << 4);
        bfr[ni] = *reinterpret_cast<const bf16x8*>((char*)Bs + off);
      }
#pragma unroll
      for (int mi = 0; mi < 4; ++mi)
#pragma unroll
        for (int ni = 0; ni < 4; ++ni)
          acc[mi][ni] = mfma16(af[mi], bfr[ni], acc[mi][ni]);
    }
  }
#pragma unroll
  for (int mi = 0; mi < 4; ++mi)
#pragma unroll
    for (int ni = 0; ni < 4; ++ni)
#pragma unroll
      for (int r = 0; r < 4; ++r) {
        int row = row0 + wm * 64 + mi * 16 + (lane >> 4) * 4 + r;
        int col = col0 + wn * 64 + ni * 16 + lr;
        float v = acc[mi][ni][r];
        if (EPI == 0) {
          ((ushort_t*)C)[(size_t)row * N + col] = f2bf(v);
        } else if (EPI == 1) {
          v += bias[col]; v = v > 0.f ? v : 0.f;
          ((ushort_t*)C)[(size_t)row * N + col] = f2bf(v);
        } else {
          v += bias[col] + resid[(size_t)row * N + col];
          ((float*)C)[(size_t)row * N + col] = v;
        }
      }
}

// --------------------------- qkv post-process ------------------------------
// heads[T*B][1536] -> q_ac,q_bd,k in [B*NH][T][64] layout; q gets bias + 1/8 scale
__global__ __launch_bounds__(256)
void qkv_post_k(const ushort_t* __restrict__ heads, const float* __restrict__ rwb,
                const float* __restrict__ rrb, ushort_t* __restrict__ q_ac,
                ushort_t* __restrict__ q_bd, ushort_t* __restrict__ kout) {
  int row = blockIdx.x;             // t*2+b
  int t = row >> 1, b = row & 1;
#pragma unroll
  for (int c0 = 0; c0 < 1024; c0 += 256) {
    int c = c0 + threadIdx.x;
    ushort_t hv = heads[(size_t)row * 1536 + c];
    if (c < 512) {
      int n = c >> 6, dh = c & 63;
      size_t o = ((size_t)(b * 8 + n) * 2048 + t) * 64 + dh;
      float q = bf2f(hv);
      q_ac[o] = f2bf((q + rwb[c]) * 0.125f);
      q_bd[o] = f2bf((q + rrb[c]) * 0.125f);
    } else {
      int cc = c - 512;
      int n = cc >> 6, dh = cc & 63;
      kout[((size_t)(b * 8 + n) * 2048 + t) * 64 + dh] = hv;
    }
  }
}

// V transpose: heads v-cols -> vt [B*NH][64][2048]
__global__ __launch_bounds__(256)
void v_trans_k(const ushort_t* __restrict__ heads, ushort_t* __restrict__ vt) {
  __shared__ float tile[64][65];
  int tt0 = blockIdx.x * 64;
  int bn = blockIdx.y;              // b*8+n
  int b = bn >> 3, n = bn & 7;
  int tid = threadIdx.x;
#pragma unroll
  for (int i = 0; i < 16; ++i) {
    int rr = i * 4 + (tid >> 6);
    int cc = tid & 63;
    tile[rr][cc] = bf2f(heads[(size_t)((tt0 + rr) * 2 + b) * 1536 + 1024 + n * 64 + cc]);
  }
  __syncthreads();
#pragma unroll
  for (int i = 0; i < 16; ++i) {
    int dh = i * 4 + (tid >> 6);
    int tt = tid & 63;
    vt[((size_t)bn * 64 + dh) * 2048 + tt0 + tt] = f2bf(tile[tt][dh]);
  }
}

// rk reverse: rkraw[2048][512] -> rkrev [NH][2048][64], rkrev[n][d] = rk[2047-d]
__global__ __launch_bounds__(256)
void rk_rev_k(const ushort_t* __restrict__ rkraw, ushort_t* __restrict__ rkrev) {
  int dist = blockIdx.x;
  int src = 2047 - dist;
#pragma unroll
  for (int c0 = 0; c0 < 512; c0 += 256) {
    int c = c0 + threadIdx.x;
    int n = c >> 6, dh = c & 63;
    rkrev[((size_t)n * 2048 + dist) * 64 + dh] = rkraw[(size_t)src * 512 + c];
  }
}

// ----------------------------- attention -----------------------------------
// grid (T/64, B*NH, 2 dirs), 256 thr. Each wave owns 16 query rows.
// score = (q+rwb).k + (q+rrb).rk_rev[i-j]   (1/8 folded into q_ac/q_bd)
__global__ __launch_bounds__(256)
void attn_k(const char* __restrict__ wsb, ushort_t* __restrict__ outp) {
  __shared__ ushort_t Ks[64 * 64];      // [j][dh]  swizzled
  __shared__ ushort_t Vs[64 * 64];      // [dh][j]  swizzled
  __shared__ ushort_t Bnd[128 * 64];    // [d_local][dh] swizzled
  __shared__ ushort_t Gs[4][16 * 80];   // per-wave BD band result (bf16)
  __shared__ ushort_t Ps[4][16 * 64];   // per-wave P (bf16, swizzled)

  const int tid = threadIdx.x;
  const int lane = tid & 63;
  const int w = tid >> 6;
  const int lr = lane & 15;
  const int lq = lane >> 4;
  const int lkb = lq * 8;

  const int dir = blockIdx.z;
  const ushort_t* qac  = (const ushort_t*)(wsb + (dir ? O_QAC_B : O_QAC_F));
  const ushort_t* qbd  = (const ushort_t*)(wsb + (dir ? O_QBD_B : O_QBD_F));
  const ushort_t* kkv  = (const ushort_t*)(wsb + (dir ? O_KK_B  : O_KK_F));
  const ushort_t* vtp  = (const ushort_t*)(wsb + (dir ? O_VT_B  : O_VT_F));
  const ushort_t* rkrev= (const ushort_t*)(wsb + (dir ? O_RKREV_B : O_RKREV_F));
  const int colbase = dir ? 512 : 0;

  const int i0 = blockIdx.x * 64;
  const int bn = blockIdx.y;
  const size_t hb = (size_t)bn * 2048;
  const size_t vb = (size_t)bn * 64;
  const size_t nb = (size_t)(bn & 7) * 2048;
  const int iw0 = i0 + w * 16;

  bf16x8 qa[2], qb[2];
#pragma unroll
  for (int kf = 0; kf < 2; ++kf) {
    size_t off = (hb + iw0 + lr) * 64 + kf * 32 + lkb;
    qa[kf] = *reinterpret_cast<const bf16x8*>(qac + off);
    qb[kf] = *reinterpret_cast<const bf16x8*>(qbd + off);
  }

  const f32x4 fz = {0.f, 0.f, 0.f, 0.f};
  float mrow[4], lrowv[4];
  f32x4 Oa[4];
#pragma unroll
  for (int r = 0; r < 4; ++r) { mrow[r] = -1e30f; lrowv[r] = 0.f; }
#pragma unroll
  for (int nf = 0; nf < 4; ++nf) Oa[nf] = fz;

  const int NT = blockIdx.x + 1;
  for (int jt = 0; jt < NT; ++jt) {
    const int j0 = jt * 64;
    __syncthreads();
    // stage K [j][dh] and Vt [dh][j]
#pragma unroll
    for (int it = 0; it < 2; ++it) {
      int li = it * 256 + tid;
      int r = li >> 3;
      int c = (li & 7) * 8;
      int off = (r * 128 + c * 2) ^ ((r & 7) << 4);
      us8 kv = *reinterpret_cast<const us8*>(kkv + (hb + j0 + r) * 64 + c);
      *reinterpret_cast<us8*>((char*)Ks + off) = kv;
      us8 vv = *reinterpret_cast<const us8*>(vtp + (vb + r) * 2048 + j0 + c);
      *reinterpret_cast<us8*>((char*)Vs + off) = vv;
    }
    // stage rel-pos band: row rb -> rk_rev[i0 - j0 - 63 + rb]
#pragma unroll
    for (int it = 0; it < 4; ++it) {
      int li = it * 256 + tid;
      int rb = li >> 3;
      int c = (li & 7) * 8;
      int d = i0 - j0 - 63 + rb;
      d = d < 0 ? 0 : (d > 2047 ? 2047 : d);
      int off = (rb * 128 + c * 2) ^ ((rb & 7) << 4);
      us8 bv = *reinterpret_cast<const us8*>(rkrev + (nb + d) * 64 + c);
      *reinterpret_cast<us8*>((char*)Bnd + off) = bv;
    }
    __syncthreads();
    if (j0 <= iw0 + 15) {
      f32x4 S[4], G[5];
#pragma unroll
      for (int nf = 0; nf < 4; ++nf) S[nf] = fz;
#pragma unroll
      for (int ng = 0; ng < 5; ++ng) G[ng] = fz;
#pragma unroll
      for (int kf = 0; kf < 2; ++kf) {
#pragma unroll
        for (int nf = 0; nf < 4; ++nf) {
          int r = nf * 16 + lr;
          int off = (r * 128 + (kf * 32 + lkb) * 2) ^ ((r & 7) << 4);
          S[nf] = mfma16(qa[kf], *reinterpret_cast<const bf16x8*>((char*)Ks + off), S[nf]);
        }
#pragma unroll
        for (int ng = 0; ng < 5; ++ng) {
          int r = w * 16 + ng * 16 + lr;   // wave's band slice starts at 16w
          int off = (r * 128 + (kf * 32 + lkb) * 2) ^ ((r & 7) << 4);
          G[ng] = mfma16(qb[kf], *reinterpret_cast<const bf16x8*>((char*)Bnd + off), G[ng]);
        }
      }
      // dump G to LDS (bf16), then gather the shifted diagonal into S
#pragma unroll
      for (int ng = 0; ng < 5; ++ng)
#pragma unroll
        for (int r = 0; r < 4; ++r) {
          int il = lq * 4 + r;
          Gs[w][il * 80 + ng * 16 + lr] = f2bf(G[ng][r]);
        }
      asm volatile("s_waitcnt lgkmcnt(0)" ::: "memory");
      float Sv[4][4];
#pragma unroll
      for (int nf = 0; nf < 4; ++nf)
#pragma unroll
        for (int r = 0; r < 4; ++r) {
          int il = lq * 4 + r;
          int jl = nf * 16 + lr;
          float sv = S[nf][r] + bf2f(Gs[w][il * 80 + (il - jl + 63)]);
          Sv[nf][r] = (j0 + jl <= iw0 + il) ? sv : -1e30f;
        }
      // online softmax update (per-row stats live in each 16-lane group)
#pragma unroll
      for (int r = 0; r < 4; ++r) {
        float m0 = fmaxf(fmaxf(Sv[0][r], Sv[1][r]), fmaxf(Sv[2][r], Sv[3][r]));
#pragma unroll
        for (int mm = 8; mm >= 1; mm >>= 1) m0 = fmaxf(m0, __shfl_xor(m0, mm, 16));
        float mnew = fmaxf(mrow[r], m0);
        float sc = __expf(mrow[r] - mnew);
        mrow[r] = mnew;
        float rsum = 0.f;
#pragma unroll
        for (int nf = 0; nf < 4; ++nf) {
          float p = __expf(Sv[nf][r] - mnew);
          rsum += p;
          int il = lq * 4 + r;
          int off = (il * 128 + (nf * 16 + lr) * 2) ^ ((il & 7) << 4);
          *(ushort_t*)((char*)&Ps[w][0] + off) = f2bf(p);
        }
#pragma unroll
        for (int mm = 8; mm >= 1; mm >>= 1) rsum += __shfl_xor(rsum, mm, 16);
        lrowv[r] = lrowv[r] * sc + rsum;
#pragma unroll
        for (int nf = 0; nf < 4; ++nf) Oa[nf][r] *= sc;
      }
      asm volatile("s_waitcnt lgkmcnt(0)" ::: "memory");
      // O += P * V
#pragma unroll
      for (int kf = 0; kf < 2; ++kf) {
        int aoff = (lr * 128 + (kf * 32 + lkb) * 2) ^ ((lr & 7) << 4);
        bf16x8 pa = *reinterpret_cast<const bf16x8*>((char*)&Ps[w][0] + aoff);
#pragma unroll
        for (int nf = 0; nf < 4; ++nf) {
          int r = nf * 16 + lr;
          int voff = (r * 128 + (kf * 32 + lkb) * 2) ^ ((r & 7) << 4);
          Oa[nf] = mfma16(pa, *reinterpret_cast<const bf16x8*>((char*)Vs + voff), Oa[nf]);
        }
      }
    }
  }
  // epilogue: O / l, write to concat buffer (bwd rows flipped back)
  const int b = bn >> 3;
  const int n = bn & 7;
#pragma unroll
  for (int r = 0; r < 4; ++r) {
    int il = lq * 4 + r;
    int ig = iw0 + il;
    int tout = dir ? (2047 - ig) : ig;
    float invl = 1.f / lrowv[r];
    size_t orow = ((size_t)tout * 2 + b) * 1024 + colbase + n * 64;
#pragma unroll
    for (int nf = 0; nf < 4; ++nf)
      outp[orow + nf * 16 + lr] = f2bf(Oa[nf][r] * invl);
  }
}

// ------------------------------- host --------------------------------------
extern "C" void kernel_launch(void* const* d_in, const int* in_sizes, int n_in,
                              void* d_out, int out_size, void* d_ws, size_t ws_size,
                              hipStream_t stream) {
  (void)in_sizes; (void)n_in; (void)out_size; (void)ws_size;
  const float* x    = (const float*)d_in[0];
  const float* pos  = (const float*)d_in[1];
  const float* ln1g = (const float*)d_in[4];
  const float* ln1b = (const float*)d_in[5];
  const float* ln2g = (const float*)d_in[6];
  const float* ln2b = (const float*)d_in[7];
  const float* ln3g = (const float*)d_in[8];
  const float* ln3b = (const float*)d_in[9];
  const float* qkvf = (const float*)d_in[10];
  const float* rnetf= (const float*)d_in[11];
  const float* rwbf = (const float*)d_in[12];
  const float* rrbf = (const float*)d_in[13];
  const float* qkvb = (const float*)d_in[14];
  const float* rnetb= (const float*)d_in[15];
  const float* rwbb = (const float*)d_in[16];
  const float* rrbb = (const float*)d_in[17];
  const float* wo   = (const float*)d_in[18];
  const float* bo   = (const float*)d_in[19];
  const float* w1   = (const float*)d_in[20];
  const float* b1   = (const float*)d_in[21];
  const float* w2   = (const float*)d_in[22];
  const float* b2   = (const float*)d_in[23];
  float* out = (float*)d_out;
  char* ws = (char*)d_ws;
  auto U = [&](size_t off) { return (ushort_t*)(ws + off); };

  auto cvt = [&](const float* src, size_t dst, int n) {
    int n4 = n / 4;
    cvt_bf16_k<<<dim3((n4 + 255) / 256), dim3(256), 0, stream>>>(src, U(dst), n4);
  };
  // weights + pos to bf16
  cvt(qkvf, O_QKV_F, 1536 * 1024);
  cvt(qkvb, O_QKV_B, 1536 * 1024);
  cvt(rnetf, O_RNET_F, 512 * 1024);
  cvt(rnetb, O_RNET_B, 512 * 1024);
  cvt(wo, O_WO, 1024 * 1024);
  cvt(w1, O_W1, 4096 * 1024);
  cvt(w2, O_W2, 1024 * 4096);
  cvt(pos, O_POS, 2048 * 1024);

  // dual LN (ln2 written row-flipped)
  ln_dual_k<<<dim3(4096), dim3(256), 0, stream>>>(x, ln1g, ln1b, ln2g, ln2b, U(O_LN1), U(O_LN2));

  // QKV + rk GEMMs
  gemm_bt<0><<<dim3(12, 32), dim3(256), 0, stream>>>(U(O_LN1), U(O_QKV_F), U(O_HEADS_F), nullptr, nullptr, 4096, 1536, 1024);
  gemm_bt<0><<<dim3(12, 32), dim3(256), 0, stream>>>(U(O_LN2), U(O_QKV_B), U(O_HEADS_B), nullptr, nullptr, 4096, 1536, 1024);
  gemm_bt<0><<<dim3(4, 16), dim3(256), 0, stream>>>(U(O_POS), U(O_RNET_F), U(O_RKRAW_F), nullptr, nullptr, 2048, 512, 1024);
  gemm_bt<0><<<dim3(4, 16), dim3(256), 0, stream>>>(U(O_POS), U(O_RNET_B), U(O_RKRAW_B), nullptr, nullptr, 2048, 512, 1024);

  // head-layout rearranges
  qkv_post_k<<<dim3(4096), dim3(256), 0, stream>>>(U(O_HEADS_F), rwbf, rrbf, U(O_QAC_F), U(O_QBD_F), U(O_KK_F));
  qkv_post_k<<<dim3(4096), dim3(256), 0, stream>>>(U(O_HEADS_B), rwbb, rrbb, U(O_QAC_B), U(O_QBD_B), U(O_KK_B));
  v_trans_k<<<dim3(32, 16), dim3(256), 0, stream>>>(U(O_HEADS_F), U(O_VT_F));
  v_trans_k<<<dim3(32, 16), dim3(256), 0, stream>>>(U(O_HEADS_B), U(O_VT_B));
  rk_rev_k<<<dim3(2048), dim3(256), 0, stream>>>(U(O_RKRAW_F), U(O_RKREV_F));
  rk_rev_k<<<dim3(2048), dim3(256), 0, stream>>>(U(O_RKRAW_B), U(O_RKREV_B));

  // attention (fwd + bwd via grid.z)
  attn_k<<<dim3(32, 16, 2), dim3(256), 0, stream>>>(ws, U(O_ACAT));

  // output projection + residual -> h (f32)
  gemm_bt<2><<<dim3(8, 32), dim3(256), 0, stream>>>(U(O_ACAT), U(O_WO), ws + O_H, bo, x, 4096, 1024, 1024);

  // FFN
  ln_one_k<<<dim3(4096), dim3(256), 0, stream>>>((const float*)(ws + O_H), ln3g, ln3b, U(O_LN3));
  gemm_bt<1><<<dim3(32, 32), dim3(256), 0, stream>>>(U(O_LN3), U(O_W1), U(O_FFNM), b1, nullptr, 4096, 4096, 1024);
  gemm_bt<2><<<dim3(8, 32), dim3(256), 0, stream>>>(U(O_FFNM), U(O_W2), out, b2, (const float*)(ws + O_H), 4096, 1024, 4096);
}